// Round 6
// baseline (666.807 us; speedup 1.0000x reference)
//
#include <hip/hip_runtime.h>
#include <hip/hip_bf16.h>
#include <math.h>

// Problem constants
#define BB 512
#define LL 10000
#define HH 2
#define NN 32
#define NL 4
#define TT 64
#define CHK 157            // ceil(10000/64); chunk 156 has 16 valid steps
#define SU_STRIDE 66       // u chunk stride in LDS (pad 2: 8B-aligned, <=2-way banks)
#define SU_CH (CHK*SU_STRIDE)   // 10362 floats per channel

typedef _Float16 half8 __attribute__((ext_vector_type(8)));
typedef float f32x4 __attribute__((ext_vector_type(4)));

// ---------------------------------------------------------------- setup 1: scalar tables
__global__ void setup_kernel(const float* __restrict__ log_dt,
                             const float* __restrict__ log_A_real,
                             const float* __restrict__ A_imag,
                             const float* __restrict__ Cin,
                             float* __restrict__ lam, float* __restrict__ lamT,
                             float* __restrict__ Cn, float* __restrict__ Kt,
                             float* __restrict__ P) {
    int ih = blockIdx.x;          // 0..7 = layer*H + h
    int tid = threadIdx.x;        // 0..63
    __shared__ float s_dtA[NN * 2];
    __shared__ float s_Cn[NN * 2];
    float dt = expf(log_dt[ih]);
    if (tid < NN) {
        int n = tid;
        float aRe = -expf(log_A_real[ih * NN + n]);
        float aIm = A_imag[ih * NN + n];
        float dRe = aRe * dt, dIm = aIm * dt;
        s_dtA[2 * n] = dRe; s_dtA[2 * n + 1] = dIm;
        float e = expf(dRe);
        float sn, cs; sincosf(dIm, &sn, &cs);
        float lRe = e * cs, lIm = e * sn;
        lam[ih * NN * 2 + 2 * n] = lRe;
        lam[ih * NN * 2 + 2 * n + 1] = lIm;
        float eT = expf((float)TT * dRe);
        float snT, csT; sincosf((float)TT * dIm, &snT, &csT);
        lamT[ih * NN * 2 + 2 * n] = eT * csT;
        lamT[ih * NN * 2 + 2 * n + 1] = eT * snT;
        float C0 = Cin[(ih * NN + n) * 2];
        float C1 = Cin[(ih * NN + n) * 2 + 1];
        float numRe = lRe - 1.0f, numIm = lIm;
        float den = aRe * aRe + aIm * aIm;
        float qRe = (numRe * aRe + numIm * aIm) / den;
        float qIm = (numIm * aRe - numRe * aIm) / den;
        float cnRe = C0 * qRe - C1 * qIm;
        float cnIm = C0 * qIm + C1 * qRe;
        Cn[ih * NN * 2 + 2 * n] = cnRe;
        Cn[ih * NN * 2 + 2 * n + 1] = cnIm;
        s_Cn[2 * n] = cnRe; s_Cn[2 * n + 1] = cnIm;
        for (int l = 0; l < TT; l++) {
            float p = (float)(l + 1);
            float ee = expf(p * dRe);
            float ss, cc; sincosf(p * dIm, &ss, &cc);
            P[(ih * NN + n) * TT * 2 + 2 * l]     = ee * cc;
            P[(ih * NN + n) * TT * 2 + 2 * l + 1] = ee * ss;
        }
    }
    __syncthreads();
    int d = tid;
    float acc = 0.0f;
    for (int n = 0; n < NN; n++) {
        float dRe = s_dtA[2 * n], dIm = s_dtA[2 * n + 1];
        float ee = expf((float)d * dRe);
        float ss, cc; sincosf((float)d * dIm, &ss, &cc);
        acc += s_Cn[2 * n] * (ee * cc) - s_Cn[2 * n + 1] * (ee * ss);
    }
    Kt[ih * TT + d] = 2.0f * acc;
}

// ---------------------------------------------------------------- setup 2: A/E fragments (fp16 hi/lo)
__global__ void setup2_kernel(const float* __restrict__ Kt,
                              const float* __restrict__ P,
                              _Float16* __restrict__ AF,
                              _Float16* __restrict__ EF) {
    int ih = blockIdx.x;       // layer*2+ch
    int lane = threadIdx.x;    // 0..63
    for (int kt = 0; kt < 4; kt++) {
        for (int lt = 0; lt < 4; lt++) {
            int l = lt * 16 + (lane & 15);
            int kbase = kt * 32 + (lane >> 4) * 8;
            for (int j = 0; j < 8; j++) {
                int k = kbase + j;
                float v;
                if (k < 64) {
                    int d = l - k;
                    v = (d >= 0) ? Kt[ih * TT + d] : 0.0f;
                } else {
                    int j2 = k - 64;
                    int n = j2 >> 1;
                    float pre = P[(ih * NN + n) * TT * 2 + 2 * l];
                    float pim = P[(ih * NN + n) * TT * 2 + 2 * l + 1];
                    v = (j2 & 1) ? (-2.0f * pim) : (2.0f * pre);
                }
                float hi = __uint_as_float(__float_as_uint(v) & 0xFFFFE000u);
                float lo = v - hi;
                size_t o0 = ((((size_t)ih * 2 + 0) * 4 + kt) * 4 + lt) * 512 + lane * 8 + j;
                size_t o1 = ((((size_t)ih * 2 + 1) * 4 + kt) * 4 + lt) * 512 + lane * 8 + j;
                AF[o0] = (_Float16)hi;
                AF[o1] = (_Float16)lo;
            }
        }
    }
    for (int kt = 0; kt < 2; kt++) {
        for (int lt = 0; lt < 4; lt++) {
            int row = lt * 16 + (lane & 15);
            int n = row >> 1, isIm = row & 1;
            int kbase = kt * 32 + (lane >> 4) * 8;
            for (int j = 0; j < 8; j++) {
                int k = kbase + j;
                int pw = 63 - k;
                float v;
                if (pw == 0) v = isIm ? 0.0f : 1.0f;
                else v = P[(ih * NN + n) * TT * 2 + 2 * (pw - 1) + isIm];
                float hi = __uint_as_float(__float_as_uint(v) & 0xFFFFE000u);
                float lo = v - hi;
                size_t o0 = ((((size_t)ih * 2 + 0) * 2 + kt) * 4 + lt) * 512 + lane * 8 + j;
                size_t o1 = ((((size_t)ih * 2 + 1) * 2 + kt) * 4 + lt) * 512 + lane * 8 + j;
                EF[o0] = (_Float16)hi;
                EF[o1] = (_Float16)lo;
            }
        }
    }
}

__device__ __forceinline__ void splitB(const f32x4& f0, const f32x4& f1,
                                       half8& Bh, half8& Bl) {
#pragma unroll
    for (int e = 0; e < 8; e++) {
        float v = (e < 4) ? f0[e] : f1[e - 4];
        float hi = __uint_as_float(__float_as_uint(v) & 0xFFFFE000u);
        Bh[e] = (_Float16)hi;
        Bl[e] = (_Float16)(v - hi);
    }
}

// state GEMM: v = E * u_chunk, writes raw chunk-final states into s_st (swizzled)
__device__ __forceinline__ void stateGemmStore(const half8* Bh, const half8* Bl,
        const _Float16* __restrict__ EFl, float* s_st, int c, int lane) {
    int quad = lane >> 4;
    f32x4 eacc[4][2];
#pragma unroll
    for (int lt = 0; lt < 4; lt++)
#pragma unroll
        for (int ch = 0; ch < 2; ch++) eacc[lt][ch] = (f32x4){0.f, 0.f, 0.f, 0.f};
#pragma unroll
    for (int ch = 0; ch < 2; ch++)
#pragma unroll
        for (int kt = 0; kt < 2; kt++) {
            const _Float16* efb = EFl + ch * 8192 + kt * 2048 + lane * 8;
            half8 bh = Bh[ch * 2 + kt], bl = Bl[ch * 2 + kt];
#pragma unroll
            for (int lt = 0; lt < 4; lt++) {
                half8 Eh = *(const half8*)(efb + lt * 512);
                half8 El = *(const half8*)(efb + 4096 + lt * 512);
                eacc[lt][ch] = __builtin_amdgcn_mfma_f32_16x16x32_f16(Eh, bh, eacc[lt][ch], 0, 0, 0);
                eacc[lt][ch] = __builtin_amdgcn_mfma_f32_16x16x32_f16(Eh, bl, eacc[lt][ch], 0, 0, 0);
                eacc[lt][ch] = __builtin_amdgcn_mfma_f32_16x16x32_f16(El, bh, eacc[lt][ch], 0, 0, 0);
            }
        }
    if (c < CHK) {
#pragma unroll
        for (int ch = 0; ch < 2; ch++)
#pragma unroll
            for (int lt = 0; lt < 4; lt++) {
                int idx = ch * 64 + lt * 16 + quad * 4;
                int p0 = (idx + 2 * c) & 127;
                int p1 = (idx + 2 + 2 * c) & 127;
                *(float2*)(s_st + c * 128 + p0) = make_float2(eacc[lt][ch][0], eacc[lt][ch][1]);
                *(float2*)(s_st + c * 128 + p1) = make_float2(eacc[lt][ch][2], eacc[lt][ch][3]);
            }
    }
}

__device__ __forceinline__ void loadUFrag(const float* s_u, int ch, int cc, int kt, int quad,
                                          half8& bh, half8& bl) {
    const float* p = s_u + ch * SU_CH + cc * SU_STRIDE + kt * 32 + quad * 8;
    float2 a = *(const float2*)p;
    float2 b = *(const float2*)(p + 2);
    float2 c = *(const float2*)(p + 4);
    float2 d = *(const float2*)(p + 6);
    f32x4 f0 = {a.x, a.y, b.x, b.y};
    f32x4 f1 = {c.x, c.y, d.x, d.y};
    splitB(f0, f1, bh, bl);
}

// ---------------------------------------------------------------- mega kernel: one block per sequence
__global__ __launch_bounds__(512) void mega_kernel(
        const float* __restrict__ x,
        const float* __restrict__ W1, const float* __restrict__ b1,
        const float* __restrict__ lamT, const float* __restrict__ CnT,
        const _Float16* __restrict__ AF, const _Float16* __restrict__ EF,
        const float* __restrict__ Dp, const float* __restrict__ Wout,
        const float* __restrict__ bout,
        const float* __restrict__ W2, const float* __restrict__ b2,
        float* __restrict__ out) {
    __shared__ float s_u[2 * SU_CH];      // 82896 B
    __shared__ float s_st[CHK * 128];     // 80384 B  (total 163280 <= 163840)
    const int tid = threadIdx.x;
    const int w8 = tid >> 6;
    const int lane = tid & 63;
    const int quad = lane >> 4;
    const int li = lane & 15;
    const int b = blockIdx.x;

    // ---- embed x -> u0 in LDS
    {
        const float w10 = W1[0], w11 = W1[1], w12 = W1[2];
        const float w13 = W1[3], w14 = W1[4], w15 = W1[5];
        const float bb0 = b1[0], bb1 = b1[1];
        for (int g = tid; g < 2500; g += 512) {
            int l = 4 * g;
            const float4* xp = (const float4*)(x + ((size_t)b * LL + l) * 3);
            float4 xa = xp[0], xb = xp[1], xc = xp[2];
            float t0[3] = {xa.x, xa.y, xa.z}, t1[3] = {xa.w, xb.x, xb.y};
            float t2[3] = {xb.z, xb.w, xc.x}, t3[3] = {xc.y, xc.z, xc.w};
            int c = l >> 6, t = l & 63;
            float u00 = fmaf(w10, t0[0], fmaf(w11, t0[1], fmaf(w12, t0[2], bb0)));
            float u01 = fmaf(w10, t1[0], fmaf(w11, t1[1], fmaf(w12, t1[2], bb0)));
            float u02 = fmaf(w10, t2[0], fmaf(w11, t2[1], fmaf(w12, t2[2], bb0)));
            float u03 = fmaf(w10, t3[0], fmaf(w11, t3[1], fmaf(w12, t3[2], bb0)));
            float u10 = fmaf(w13, t0[0], fmaf(w14, t0[1], fmaf(w15, t0[2], bb1)));
            float u11 = fmaf(w13, t1[0], fmaf(w14, t1[1], fmaf(w15, t1[2], bb1)));
            float u12 = fmaf(w13, t2[0], fmaf(w14, t2[1], fmaf(w15, t2[2], bb1)));
            float u13 = fmaf(w13, t3[0], fmaf(w14, t3[1], fmaf(w15, t3[2], bb1)));
            float* p0 = s_u + c * SU_STRIDE + t;
            float* p1 = p0 + SU_CH;
            *(float2*)p0 = make_float2(u00, u01);
            *(float2*)(p0 + 2) = make_float2(u02, u03);
            *(float2*)p1 = make_float2(u10, u11);
            *(float2*)(p1 + 2) = make_float2(u12, u13);
        }
        if (tid < 96) {   // zero tail of partial chunk 156 (t = 16..63, both ch)
            int ch = tid / 48, t = 16 + (tid % 48);
            s_u[ch * SU_CH + 156 * SU_STRIDE + t] = 0.0f;
        }
    }
    __syncthreads();

    // ---- initial state GEMM (layer 0 chunk-final states)
    for (int T = w8; T < 10; T += 8) {
        int c = T * 16 + li;
        int cc = (c < CHK) ? c : (CHK - 1);
        half8 Bh[4], Bl[4];
#pragma unroll
        for (int ch = 0; ch < 2; ch++)
#pragma unroll
            for (int kt = 0; kt < 2; kt++)
                loadUFrag(s_u, ch, cc, kt, quad, Bh[ch * 2 + kt], Bl[ch * 2 + kt]);
        stateGemmStore(Bh, Bl, EF, s_st, c, lane);
    }
    __syncthreads();

    // ---- layer loop
    for (int i = 0; i < NL; i++) {
        const bool isLast = (i == NL - 1);

        // cross-chunk scan (wave 0 only): v -> w in place
        if (w8 == 0) {
            int h = lane >> 5, n = lane & 31;
            float lRe = lamT[(i * HH + h) * NN * 2 + 2 * n];
            float lIm = lamT[(i * HH + h) * NN * 2 + 2 * n + 1];
            float cRe = CnT[(i * HH + h) * NN * 2 + 2 * n];
            float cIm = CnT[(i * HH + h) * NN * 2 + 2 * n + 1];
            int idx0 = h * 64 + 2 * n;
            float rRe = 0.f, rIm = 0.f;
            float2 v = *(const float2*)(s_st + (idx0 & 127));
            for (int c = 0; c < CHK; c++) {
                float2 vc = v;
                if (c + 1 < CHK) {
                    int pn = (idx0 + 2 * (c + 1)) & 127;
                    v = *(const float2*)(s_st + (c + 1) * 128 + pn);
                }
                float wRe = cRe * rRe - cIm * rIm;
                float wIm = cRe * rIm + cIm * rRe;
                int pw = (idx0 + 2 * c) & 127;
                *(float2*)(s_st + c * 128 + pw) = make_float2(wRe, wIm);
                float tRe = fmaf(lRe, rRe, fmaf(-lIm, rIm, vc.x));
                float tIm = fmaf(lRe, rIm, fmaf(lIm, rRe, vc.y));
                rRe = tRe; rIm = tIm;
            }
        }
        __syncthreads();

        float D0 = Dp[i * HH + 0], D1 = Dp[i * HH + 1];
        const float* Wo = Wout + i * 8;
        const float* bo = bout + i * 4;
        float w20 = W2[0], w21 = W2[1], w22 = W2[2], w23 = W2[3];
        float b20 = b2[0], b21 = b2[1];

        for (int T = w8; T < 10; T += 8) {
            int c = T * 16 + li;
            int cc = (c < CHK) ? c : (CHK - 1);
            bool cOK = (c < CHK);

            // B operands: u (split) and w (already fp32 in LDS, split here)
            half8 uh[2][2], ul2[2][2], wh[2][2], wl[2][2];
#pragma unroll
            for (int ch = 0; ch < 2; ch++)
#pragma unroll
                for (int kt = 0; kt < 2; kt++)
                    loadUFrag(s_u, ch, cc, kt, quad, uh[ch][kt], ul2[ch][kt]);
#pragma unroll
            for (int ch = 0; ch < 2; ch++)
#pragma unroll
                for (int k2 = 0; k2 < 2; k2++) {
                    int idx2 = ch * 64 + k2 * 32 + quad * 8;
                    float tmp[8];
#pragma unroll
                    for (int jj = 0; jj < 4; jj++) {
                        int pp = (idx2 + 2 * jj + 2 * cc) & 127;
                        float2 vv = *(const float2*)(s_st + cc * 128 + pp);
                        tmp[2 * jj] = vv.x; tmp[2 * jj + 1] = vv.y;
                    }
                    f32x4 f0 = {tmp[0], tmp[1], tmp[2], tmp[3]};
                    f32x4 f1 = {tmp[4], tmp[5], tmp[6], tmp[7]};
                    splitB(f0, f1, wh[ch][k2], wl[ch][k2]);
                }

            // Y-GEMM
            f32x4 acc[4][2];
#pragma unroll
            for (int lt = 0; lt < 4; lt++)
#pragma unroll
                for (int ch = 0; ch < 2; ch++) acc[lt][ch] = (f32x4){0.f, 0.f, 0.f, 0.f};
#pragma unroll
            for (int kt = 0; kt < 4; kt++)
#pragma unroll
                for (int ch = 0; ch < 2; ch++) {
                    const _Float16* afb = AF + (size_t)(i * 2 + ch) * 16384 + kt * 2048 + lane * 8;
                    half8 Bh = (kt < 2) ? uh[ch][kt] : wh[ch][kt - 2];
                    half8 Bl = (kt < 2) ? ul2[ch][kt] : wl[ch][kt - 2];
#pragma unroll
                    for (int lt = 0; lt < 4; lt++) {
                        half8 Ah = *(const half8*)(afb + lt * 512);
                        half8 Al = *(const half8*)(afb + 8192 + lt * 512);
                        acc[lt][ch] = __builtin_amdgcn_mfma_f32_16x16x32_f16(Ah, Bh, acc[lt][ch], 0, 0, 0);
                        acc[lt][ch] = __builtin_amdgcn_mfma_f32_16x16x32_f16(Ah, Bl, acc[lt][ch], 0, 0, 0);
                        acc[lt][ch] = __builtin_amdgcn_mfma_f32_16x16x32_f16(Al, Bh, acc[lt][ch], 0, 0, 0);
                    }
                }

            // epilogue: D-skip, GELU, 1x1 mix, GLU
            f32x4 r0f[4], r1f[4];
#pragma unroll
            for (int lt = 0; lt < 4; lt++) {
                int l = lt * 16 + quad * 4;
                const float* pu0 = s_u + cc * SU_STRIDE + l;
                const float* pu1 = pu0 + SU_CH;
                float2 ua = *(const float2*)pu0, ub = *(const float2*)(pu0 + 2);
                float2 uc = *(const float2*)pu1, ud = *(const float2*)(pu1 + 2);
                f32x4 u0 = {ua.x, ua.y, ub.x, ub.y};
                f32x4 u1 = {uc.x, uc.y, ud.x, ud.y};
                f32x4 r0, r1;
#pragma unroll
                for (int r = 0; r < 4; r++) {
                    float a0 = fmaf(D0, u0[r], acc[lt][0][r]);
                    float a1 = fmaf(D1, u1[r], acc[lt][1][r]);
                    a0 = 0.5f * a0 * (1.0f + erff(a0 * 0.70710678118654752f));
                    a1 = 0.5f * a1 * (1.0f + erff(a1 * 0.70710678118654752f));
                    float z0 = fmaf(Wo[0], a0, fmaf(Wo[1], a1, bo[0]));
                    float z1 = fmaf(Wo[2], a0, fmaf(Wo[3], a1, bo[1]));
                    float z2 = fmaf(Wo[4], a0, fmaf(Wo[5], a1, bo[2]));
                    float z3 = fmaf(Wo[6], a0, fmaf(Wo[7], a1, bo[3]));
                    float g2 = 1.0f / (1.0f + expf(-z2));
                    float g3 = 1.0f / (1.0f + expf(-z3));
                    r0[r] = z0 * g2;
                    r1[r] = z1 * g3;
                }
                r0f[lt] = r0; r1f[lt] = r1;
                bool ok = cOK && (c < CHK - 1 || lt == 0);
                if (!isLast) {
                    if (ok) {
                        float* pd0 = s_u + cc * SU_STRIDE + l;
                        float* pd1 = pd0 + SU_CH;
                        *(float2*)pd0 = make_float2(r0[0], r0[1]);
                        *(float2*)(pd0 + 2) = make_float2(r0[2], r0[3]);
                        *(float2*)pd1 = make_float2(r1[0], r1[1]);
                        *(float2*)(pd1 + 2) = make_float2(r1[2], r1[3]);
                    }
                } else if (ok) {
                    float* op = out + ((size_t)b * LL + (size_t)cc * TT + l) * 2;
                    f32x4 lo4, hi4;
                    lo4[0] = fmaf(r0[0], w20, fmaf(r1[0], w21, b20));
                    lo4[1] = fmaf(r0[0], w22, fmaf(r1[0], w23, b21));
                    lo4[2] = fmaf(r0[1], w20, fmaf(r1[1], w21, b20));
                    lo4[3] = fmaf(r0[1], w22, fmaf(r1[1], w23, b21));
                    hi4[0] = fmaf(r0[2], w20, fmaf(r1[2], w21, b20));
                    hi4[1] = fmaf(r0[2], w22, fmaf(r1[2], w23, b21));
                    hi4[2] = fmaf(r0[3], w20, fmaf(r1[3], w21, b20));
                    hi4[3] = fmaf(r0[3], w22, fmaf(r1[3], w23, b21));
                    *(f32x4*)op = lo4;
                    *(f32x4*)(op + 4) = hi4;
                }
            }

            // fused next-layer state GEMM
            if (!isLast) {
                f32x4 rmA[4], rmB[4];
#pragma unroll
                for (int lt = 0; lt < 4; lt++) {
                    bool z = (c == CHK - 1) && (lt > 0);
                    rmA[lt] = z ? (f32x4){0.f, 0.f, 0.f, 0.f} : r0f[lt];
                    rmB[lt] = z ? (f32x4){0.f, 0.f, 0.f, 0.f} : r1f[lt];
                }
                half8 sbH[4], sbL[4];
#pragma unroll
                for (int ch = 0; ch < 2; ch++)
#pragma unroll
                    for (int kt = 0; kt < 2; kt++) {
                        float bv[8];
#pragma unroll
                        for (int j = 0; j < 8; j++) {
                            int srcLane = ((quad & 1) * 2 + (j >> 2)) * 16 + li;
                            float x0 = ch ? rmB[kt * 2 + 0][j & 3] : rmA[kt * 2 + 0][j & 3];
                            float x1 = ch ? rmB[kt * 2 + 1][j & 3] : rmA[kt * 2 + 1][j & 3];
                            float a = __shfl(x0, srcLane, 64);
                            float bb = __shfl(x1, srcLane, 64);
                            bv[j] = (quad & 2) ? bb : a;
                        }
                        half8 Bh, Bl;
#pragma unroll
                        for (int e = 0; e < 8; e++) {
                            float v = bv[e];
                            float hi = __uint_as_float(__float_as_uint(v) & 0xFFFFE000u);
                            Bh[e] = (_Float16)hi;
                            Bl[e] = (_Float16)(v - hi);
                        }
                        sbH[ch * 2 + kt] = Bh;
                        sbL[ch * 2 + kt] = Bl;
                    }
                stateGemmStore(sbH, sbL, EF + (size_t)(i + 1) * 16384, s_st, c, lane);
            }
        }
        __syncthreads();
    }
}

extern "C" void kernel_launch(void* const* d_in, const int* in_sizes, int n_in,
                              void* d_out, int out_size, void* d_ws, size_t ws_size,
                              hipStream_t stream) {
    const float* x         = (const float*)d_in[0];
    const float* W1        = (const float*)d_in[1];
    const float* b1        = (const float*)d_in[2];
    const float* W2        = (const float*)d_in[3];
    const float* b2        = (const float*)d_in[4];
    const float* log_dt    = (const float*)d_in[5];
    const float* log_A_real= (const float*)d_in[6];
    const float* A_imag    = (const float*)d_in[7];
    const float* Cin       = (const float*)d_in[8];
    const float* Dp        = (const float*)d_in[9];
    const float* Wout      = (const float*)d_in[10];
    const float* bout      = (const float*)d_in[11];
    float* out = (float*)d_out;
    float* ws = (float*)d_ws;

    float* lam  = ws;
    float* lamT = lam + 512;
    float* Cn   = lamT + 512;
    float* Kt   = Cn + 512;
    float* P    = Kt + 512;
    _Float16* AF = (_Float16*)(P + 32768);
    _Float16* EF = AF + 131072;

    setup_kernel<<<dim3(NL * HH), dim3(64), 0, stream>>>(log_dt, log_A_real, A_imag, Cin,
                                                         lam, lamT, Cn, Kt, P);
    setup2_kernel<<<dim3(NL * HH), dim3(64), 0, stream>>>(Kt, P, AF, EF);
    mega_kernel<<<dim3(BB), dim3(512), 0, stream>>>(x, W1, b1, lamT, Cn, AF, EF,
                                                    Dp, Wout, bout, W2, b2, out);
}

// Round 7
// 418.186 us; speedup vs baseline: 1.5945x; 1.5945x over previous
//
#include <hip/hip_runtime.h>
#include <hip/hip_bf16.h>
#include <math.h>

// Problem constants
#define BB 512
#define LL 10000
#define HH 2
#define NN 32
#define NL 4
#define TT 64
#define CHK 157           // ceil(10000/64)
#define CPAD 160          // padded chunks per sequence (multiple of 16)
#define BL (BB*LL)        // 5,120,000

// Workspace layout (in floats)
#define OFF_U0   0
#define OFF_U1   10240000          // B*H*L
#define OFF_S0   20480000          // raw states: B*CHK*128 = 10,289,152
#define OFF_S1   30769152          // w buffer (fp16 hi/lo planes, same bytes)
#define OFF_TAB  41058304
// tables: lam 512 | lamT 512 | Cn 512 | Kt 512 | P 32768 | AF 131072h | EF 65536h

typedef _Float16 half8 __attribute__((ext_vector_type(8)));
typedef _Float16 half2v __attribute__((ext_vector_type(2)));
typedef float f32x4 __attribute__((ext_vector_type(4)));

// ---------------------------------------------------------------- setup 1: scalar tables
__global__ void setup_kernel(const float* __restrict__ log_dt,
                             const float* __restrict__ log_A_real,
                             const float* __restrict__ A_imag,
                             const float* __restrict__ Cin,
                             float* __restrict__ lam, float* __restrict__ lamT,
                             float* __restrict__ Cn, float* __restrict__ Kt,
                             float* __restrict__ P) {
    int ih = blockIdx.x;          // 0..7 = layer*H + h
    int tid = threadIdx.x;        // 0..63
    __shared__ float s_dtA[NN * 2];
    __shared__ float s_Cn[NN * 2];
    float dt = expf(log_dt[ih]);
    if (tid < NN) {
        int n = tid;
        float aRe = -expf(log_A_real[ih * NN + n]);
        float aIm = A_imag[ih * NN + n];
        float dRe = aRe * dt, dIm = aIm * dt;
        s_dtA[2 * n] = dRe; s_dtA[2 * n + 1] = dIm;
        float e = expf(dRe);
        float sn, cs; sincosf(dIm, &sn, &cs);
        float lRe = e * cs, lIm = e * sn;
        lam[ih * NN * 2 + 2 * n] = lRe;
        lam[ih * NN * 2 + 2 * n + 1] = lIm;
        float eT = expf((float)TT * dRe);
        float snT, csT; sincosf((float)TT * dIm, &snT, &csT);
        lamT[ih * NN * 2 + 2 * n] = eT * csT;
        lamT[ih * NN * 2 + 2 * n + 1] = eT * snT;
        // Cn = (C0 + i C1) * (lam - 1) / A
        float C0 = Cin[(ih * NN + n) * 2];
        float C1 = Cin[(ih * NN + n) * 2 + 1];
        float numRe = lRe - 1.0f, numIm = lIm;
        float den = aRe * aRe + aIm * aIm;
        float qRe = (numRe * aRe + numIm * aIm) / den;
        float qIm = (numIm * aRe - numRe * aIm) / den;
        float cnRe = C0 * qRe - C1 * qIm;
        float cnIm = C0 * qIm + C1 * qRe;
        Cn[ih * NN * 2 + 2 * n] = cnRe;
        Cn[ih * NN * 2 + 2 * n + 1] = cnIm;
        s_Cn[2 * n] = cnRe; s_Cn[2 * n + 1] = cnIm;
        // P[n][l] = lam^{l+1}, l = 0..63
        for (int l = 0; l < TT; l++) {
            float p = (float)(l + 1);
            float ee = expf(p * dRe);
            float ss, cc; sincosf(p * dIm, &ss, &cc);
            P[(ih * NN + n) * TT * 2 + 2 * l]     = ee * cc;
            P[(ih * NN + n) * TT * 2 + 2 * l + 1] = ee * ss;
        }
    }
    __syncthreads();
    // Kt[d] = 2 * sum_n Re(Cn * lam^d), d = tid (0..63)
    int d = tid;
    float acc = 0.0f;
    for (int n = 0; n < NN; n++) {
        float dRe = s_dtA[2 * n], dIm = s_dtA[2 * n + 1];
        float ee = expf((float)d * dRe);
        float ss, cc; sincosf((float)d * dIm, &ss, &cc);
        acc += s_Cn[2 * n] * (ee * cc) - s_Cn[2 * n + 1] * (ee * ss);
    }
    Kt[ih * TT + d] = 2.0f * acc;
}

// ---------------------------------------------------------------- setup 2: A/E fragments (fp16 hi/lo)
__global__ void setup2_kernel(const float* __restrict__ Kt,
                              const float* __restrict__ P,
                              _Float16* __restrict__ AF,
                              _Float16* __restrict__ EF) {
    int ih = blockIdx.x;       // layer*2+ch
    int lane = threadIdx.x;    // 0..63
    for (int kt = 0; kt < 4; kt++) {
        for (int lt = 0; lt < 4; lt++) {
            int l = lt * 16 + (lane & 15);
            int kbase = kt * 32 + (lane >> 4) * 8;
            for (int j = 0; j < 8; j++) {
                int k = kbase + j;
                float v;
                if (k < 64) {
                    int d = l - k;
                    v = (d >= 0) ? Kt[ih * TT + d] : 0.0f;
                } else {
                    int j2 = k - 64;
                    int n = j2 >> 1;
                    float pre = P[(ih * NN + n) * TT * 2 + 2 * l];
                    float pim = P[(ih * NN + n) * TT * 2 + 2 * l + 1];
                    v = (j2 & 1) ? (-2.0f * pim) : (2.0f * pre);
                }
                float hi = __uint_as_float(__float_as_uint(v) & 0xFFFFE000u);
                float lo = v - hi;
                size_t o0 = ((((size_t)ih * 2 + 0) * 4 + kt) * 4 + lt) * 512 + lane * 8 + j;
                size_t o1 = ((((size_t)ih * 2 + 1) * 4 + kt) * 4 + lt) * 512 + lane * 8 + j;
                AF[o0] = (_Float16)hi;
                AF[o1] = (_Float16)lo;
            }
        }
    }
    for (int kt = 0; kt < 2; kt++) {
        for (int lt = 0; lt < 4; lt++) {
            int row = lt * 16 + (lane & 15);
            int n = row >> 1, isIm = row & 1;
            int kbase = kt * 32 + (lane >> 4) * 8;
            for (int j = 0; j < 8; j++) {
                int k = kbase + j;        // timestep 0..63
                int pw = 63 - k;          // power of lambda
                float v;
                if (pw == 0) v = isIm ? 0.0f : 1.0f;
                else v = P[(ih * NN + n) * TT * 2 + 2 * (pw - 1) + isIm];
                float hi = __uint_as_float(__float_as_uint(v) & 0xFFFFE000u);
                float lo = v - hi;
                size_t o0 = ((((size_t)ih * 2 + 0) * 2 + kt) * 4 + lt) * 512 + lane * 8 + j;
                size_t o1 = ((((size_t)ih * 2 + 1) * 2 + kt) * 4 + lt) * 512 + lane * 8 + j;
                EF[o0] = (_Float16)hi;
                EF[o1] = (_Float16)lo;
            }
        }
    }
}

// ---------------------------------------------------------------- embed (vectorized): u0 = x@W1^T + b1
__global__ __launch_bounds__(256) void embed_kernel(const float* __restrict__ x,
                             const float* __restrict__ W1, const float* __restrict__ b1,
                             float* __restrict__ u) {
    int idx = blockIdx.x * blockDim.x + threadIdx.x;   // 0..BL/4-1
    int b = idx / (LL / 4), l4 = idx - b * (LL / 4);
    int l = l4 * 4;
    const float4* xp = (const float4*)(x + ((size_t)b * LL + l) * 3);
    float4 xa = xp[0], xb = xp[1], xc = xp[2];
    float w10 = W1[0], w11 = W1[1], w12 = W1[2];
    float w13 = W1[3], w14 = W1[4], w15 = W1[5];
    float bb0 = b1[0], bb1 = b1[1];
    float t0[3] = {xa.x, xa.y, xa.z};
    float t1[3] = {xa.w, xb.x, xb.y};
    float t2[3] = {xb.z, xb.w, xc.x};
    float t3[3] = {xc.y, xc.z, xc.w};
    f32x4 u0, u1;
    u0[0] = fmaf(w10, t0[0], fmaf(w11, t0[1], fmaf(w12, t0[2], bb0)));
    u0[1] = fmaf(w10, t1[0], fmaf(w11, t1[1], fmaf(w12, t1[2], bb0)));
    u0[2] = fmaf(w10, t2[0], fmaf(w11, t2[1], fmaf(w12, t2[2], bb0)));
    u0[3] = fmaf(w10, t3[0], fmaf(w11, t3[1], fmaf(w12, t3[2], bb0)));
    u1[0] = fmaf(w13, t0[0], fmaf(w14, t0[1], fmaf(w15, t0[2], bb1)));
    u1[1] = fmaf(w13, t1[0], fmaf(w14, t1[1], fmaf(w15, t1[2], bb1)));
    u1[2] = fmaf(w13, t2[0], fmaf(w14, t2[1], fmaf(w15, t2[2], bb1)));
    u1[3] = fmaf(w13, t3[0], fmaf(w14, t3[1], fmaf(w15, t3[2], bb1)));
    *(f32x4*)(u + (size_t)(b * HH) * LL + l) = u0;
    *(f32x4*)(u + (size_t)(b * HH + 1) * LL + l) = u1;
}

__device__ __forceinline__ void splitB(const f32x4& f0, const f32x4& f1,
                                       half8& Bh, half8& Bl) {
#pragma unroll
    for (int e = 0; e < 8; e++) {
        float v = (e < 4) ? f0[e] : f1[e - 4];
        float hi = __uint_as_float(__float_as_uint(v) & 0xFFFFE000u);
        Bh[e] = (_Float16)hi;
        Bl[e] = (_Float16)(v - hi);
    }
}

// ---------------------------------------------------------------- phase A (layer 0 only): states via MFMA
__global__ __launch_bounds__(64) void phaseA_mfma(const float* __restrict__ u,
                              const _Float16* __restrict__ EF,
                              float* __restrict__ stRaw) {
    const int lane = threadIdx.x;
    const int quad = lane >> 4;
    const int li = lane & 15;
    const int col = blockIdx.x * 16 + li;
    const int b = col / CPAD;
    const int c = col - b * CPAD;
    const int cc = (c < CHK) ? c : (CHK - 1);
    const float* uB = u + (size_t)(b * HH) * LL + cc * TT;

    f32x4 eacc[4][2];
#pragma unroll
    for (int lt = 0; lt < 4; lt++)
#pragma unroll
        for (int ch = 0; ch < 2; ch++) eacc[lt][ch] = (f32x4){0.f, 0.f, 0.f, 0.f};

#pragma unroll
    for (int ch = 0; ch < 2; ch++) {
#pragma unroll
        for (int kt = 0; kt < 2; kt++) {
            const float* src = uB + ch * LL + kt * 32 + quad * 8;
            f32x4 f0 = *(const f32x4*)src;
            f32x4 f1 = *(const f32x4*)(src + 4);
            half8 Bh, Bl; splitB(f0, f1, Bh, Bl);
            const _Float16* efb = EF + (size_t)ch * 8192 + kt * 2048 + lane * 8;
#pragma unroll
            for (int lt = 0; lt < 4; lt++) {
                half8 Eh = *(const half8*)(efb + lt * 512);
                half8 El = *(const half8*)(efb + 4096 + lt * 512);
                eacc[lt][ch] = __builtin_amdgcn_mfma_f32_16x16x32_f16(Eh, Bh, eacc[lt][ch], 0, 0, 0);
                eacc[lt][ch] = __builtin_amdgcn_mfma_f32_16x16x32_f16(Eh, Bl, eacc[lt][ch], 0, 0, 0);
                eacc[lt][ch] = __builtin_amdgcn_mfma_f32_16x16x32_f16(El, Bh, eacc[lt][ch], 0, 0, 0);
            }
        }
    }
    if (c < CHK) {
        float* sp = stRaw + ((size_t)b * CHK + c) * 128;
#pragma unroll
        for (int ch = 0; ch < 2; ch++)
#pragma unroll
            for (int lt = 0; lt < 4; lt++)
                *(f32x4*)(sp + ch * 64 + lt * 16 + quad * 4) = eacc[lt][ch];
    }
}

// ---------------------------------------------------------------- phase B: cross-chunk scan, 16-deep prefetch
__global__ __launch_bounds__(64) void phaseB_kernel(const float* __restrict__ lamT,
                              const float* __restrict__ CnT,
                              const float* __restrict__ stRaw,
                              _Float16* __restrict__ stW, int layer) {
    int b = blockIdx.x;
    int lane = threadIdx.x;
    int h = lane >> 5, n = lane & 31;
    float lRe = lamT[(layer * HH + h) * NN * 2 + 2 * n];
    float lIm = lamT[(layer * HH + h) * NN * 2 + 2 * n + 1];
    float cRe = CnT[(layer * HH + h) * NN * 2 + 2 * n];
    float cIm = CnT[(layer * HH + h) * NN * 2 + 2 * n + 1];
    const float2* src = (const float2*)(stRaw + (size_t)b * CHK * 128) + lane;
    _Float16* dst = stW + (size_t)b * CHK * 256 + 2 * lane;
    float2 buf[16];
#pragma unroll
    for (int p = 0; p < 16; p++) buf[p] = src[(size_t)p * 64];
    float rRe = 0.f, rIm = 0.f;
    for (int co = 0; co < 10; co++) {
#pragma unroll
        for (int ci = 0; ci < 16; ci++) {
            int cx = co * 16 + ci;
            if (cx < CHK) {
                float2 v = buf[ci];
                if (cx + 16 < CHK) buf[ci] = src[(size_t)(cx + 16) * 64];
                float wRe = cRe * rRe - cIm * rIm;
                float wIm = cRe * rIm + cIm * rRe;
                float hRe = __uint_as_float(__float_as_uint(wRe) & 0xFFFFE000u);
                float hIm = __uint_as_float(__float_as_uint(wIm) & 0xFFFFE000u);
                half2v hv = {(_Float16)hRe, (_Float16)hIm};
                half2v lv = {(_Float16)(wRe - hRe), (_Float16)(wIm - hIm)};
                *(half2v*)(dst + (size_t)cx * 256) = hv;
                *(half2v*)(dst + (size_t)cx * 256 + 128) = lv;
                float tRe = fmaf(lRe, rRe, fmaf(-lIm, rIm, v.x));
                float tIm = fmaf(lRe, rIm, fmaf(lIm, rRe, v.y));
                rRe = tRe; rIm = tIm;
            }
        }
    }
}

// ---------------------------------------------------------------- phase C: Y-GEMM (A from LDS) + epilogue + fused state GEMM
__global__ __launch_bounds__(512, 4) void phaseC_mfma(
        const float* __restrict__ u, float* __restrict__ uNext,
        const _Float16* __restrict__ AF, const _Float16* __restrict__ EF,
        const _Float16* __restrict__ stW, float* __restrict__ stRaw,
        const float* __restrict__ Dp, const float* __restrict__ Wout,
        const float* __restrict__ bout, int layer,
        const float* __restrict__ W2, const float* __restrict__ b2,
        float* __restrict__ out, int isLast) {
    __shared__ _Float16 sAF[32768];   // 64 KB: this layer's full A-fragment table

    const int tid = threadIdx.x;
    // stage AF once per block (both channels, hi+lo)
    {
        const float4* srcA = (const float4*)(AF + (size_t)layer * 32768);
        float4* dstA = (float4*)sAF;
#pragma unroll
        for (int k = 0; k < 8; k++) dstA[tid + k * 512] = srcA[tid + k * 512];
    }
    __syncthreads();

    const int wid = tid >> 6;
    const int lane = tid & 63;
    const int quad = lane >> 4;
    const int li = lane & 15;
    const int gw = blockIdx.x * 8 + wid;         // 0..5119
    const int col = gw * 16 + li;
    const int b = col / CPAD;
    const int c = col - b * CPAD;
    const int cc = (c < CHK) ? c : (CHK - 1);
    const float* uB = u + (size_t)(b * HH) * LL + cc * TT;
    const _Float16* wB = stW + ((size_t)b * CHK + cc) * 256;

    // ---- B-operand loads
    f32x4 uf[2][2][2];          // [ch][kt][half]
#pragma unroll
    for (int ch = 0; ch < 2; ch++)
#pragma unroll
        for (int kt = 0; kt < 2; kt++) {
            const float* s = uB + ch * LL + kt * 32 + quad * 8;
            uf[ch][kt][0] = *(const f32x4*)s;
            uf[ch][kt][1] = *(const f32x4*)(s + 4);
        }
    half8 wbh[2][2], wbl[2][2];  // [ch][k2] (pre-split by phaseB)
#pragma unroll
    for (int ch = 0; ch < 2; ch++)
#pragma unroll
        for (int k2 = 0; k2 < 2; k2++) {
            const _Float16* s = wB + ch * 64 + k2 * 32 + quad * 8;
            wbh[ch][k2] = *(const half8*)s;
            wbl[ch][k2] = *(const half8*)(s + 128);
        }
    half8 uh[2][2], ul[2][2];
#pragma unroll
    for (int ch = 0; ch < 2; ch++)
#pragma unroll
        for (int kt = 0; kt < 2; kt++)
            splitB(uf[ch][kt][0], uf[ch][kt][1], uh[ch][kt], ul[ch][kt]);

    // ---- Y-GEMM, A-fragments from LDS (conflict-free ds_read_b128)
    f32x4 acc[4][2];   // [lt][ch]
#pragma unroll
    for (int lt = 0; lt < 4; lt++)
#pragma unroll
        for (int ch = 0; ch < 2; ch++) acc[lt][ch] = (f32x4){0.f, 0.f, 0.f, 0.f};

#pragma unroll
    for (int kt = 0; kt < 4; kt++) {
#pragma unroll
        for (int ch = 0; ch < 2; ch++) {
            const _Float16* afb = sAF + ch * 16384 + kt * 2048 + lane * 8;
            half8 Bh = (kt < 2) ? uh[ch][kt] : wbh[ch][kt - 2];
            half8 Bl = (kt < 2) ? ul[ch][kt] : wbl[ch][kt - 2];
#pragma unroll
            for (int lt = 0; lt < 4; lt++) {
                half8 Ah = *(const half8*)(afb + lt * 512);
                half8 Al = *(const half8*)(afb + 8192 + lt * 512);
                acc[lt][ch] = __builtin_amdgcn_mfma_f32_16x16x32_f16(Ah, Bh, acc[lt][ch], 0, 0, 0);
                acc[lt][ch] = __builtin_amdgcn_mfma_f32_16x16x32_f16(Ah, Bl, acc[lt][ch], 0, 0, 0);
                acc[lt][ch] = __builtin_amdgcn_mfma_f32_16x16x32_f16(Al, Bh, acc[lt][ch], 0, 0, 0);
            }
        }
    }

    // ---- fused epilogue
    float D0 = Dp[layer * HH + 0], D1 = Dp[layer * HH + 1];
    const float* Wo = Wout + layer * 8;
    const float* bo = bout + layer * 4;
    bool cOK = (c < CHK);
    const float LOG2E = 1.442695040888963f;
    f32x4 r0f[4], r1f[4];
#pragma unroll
    for (int lt = 0; lt < 4; lt++) {
        int l = lt * 16 + quad * 4;
        f32x4 u0 = *(const f32x4*)(uB + l);
        f32x4 u1 = *(const f32x4*)(uB + LL + l);
        f32x4 r0, r1;
#pragma unroll
        for (int r = 0; r < 4; r++) {
            float a0 = fmaf(D0, u0[r], acc[lt][0][r]);
            float a1 = fmaf(D1, u1[r], acc[lt][1][r]);
            a0 = 0.5f * a0 * (1.0f + erff(a0 * 0.70710678118654752f));
            a1 = 0.5f * a1 * (1.0f + erff(a1 * 0.70710678118654752f));
            float z0 = fmaf(Wo[0], a0, fmaf(Wo[1], a1, bo[0]));
            float z1 = fmaf(Wo[2], a0, fmaf(Wo[3], a1, bo[1]));
            float z2 = fmaf(Wo[4], a0, fmaf(Wo[5], a1, bo[2]));
            float z3 = fmaf(Wo[6], a0, fmaf(Wo[7], a1, bo[3]));
            float g2 = __builtin_amdgcn_rcpf(1.0f + __builtin_amdgcn_exp2f(-z2 * LOG2E));
            float g3 = __builtin_amdgcn_rcpf(1.0f + __builtin_amdgcn_exp2f(-z3 * LOG2E));
            r0[r] = z0 * g2;
            r1[r] = z1 * g3;
        }
        r0f[lt] = r0; r1f[lt] = r1;
        bool ok = cOK && (c < CHK - 1 || lt == 0);
        if (!isLast) {
            if (ok) {
                float* p0 = uNext + (size_t)(b * HH) * LL + cc * TT + l;
                *(f32x4*)p0 = r0;
                *(f32x4*)(p0 + LL) = r1;
            }
        } else {
            if (ok) {
                float w20 = W2[0], w21 = W2[1], w22 = W2[2], w23 = W2[3];
                float b20 = b2[0], b21 = b2[1];
                float* op = out + ((size_t)b * LL + (size_t)cc * TT + l) * 2;
                f32x4 lo4, hi4;
                lo4[0] = fmaf(r0[0], w20, fmaf(r1[0], w21, b20));
                lo4[1] = fmaf(r0[0], w22, fmaf(r1[0], w23, b21));
                lo4[2] = fmaf(r0[1], w20, fmaf(r1[1], w21, b20));
                lo4[3] = fmaf(r0[1], w22, fmaf(r1[1], w23, b21));
                hi4[0] = fmaf(r0[2], w20, fmaf(r1[2], w21, b20));
                hi4[1] = fmaf(r0[2], w22, fmaf(r1[2], w23, b21));
                hi4[2] = fmaf(r0[3], w20, fmaf(r1[3], w21, b20));
                hi4[3] = fmaf(r0[3], w22, fmaf(r1[3], w23, b21));
                *(f32x4*)op = lo4;
                *(f32x4*)(op + 4) = hi4;
            }
        }
    }

    // ---- fused next-layer state GEMM (skip on last layer)
    if (!isLast) {
        f32x4 rmA[4], rmB[4];
#pragma unroll
        for (int lt = 0; lt < 4; lt++) {
            bool z = (c == CHK - 1) && (lt > 0);   // zero-pad partial chunk
            rmA[lt] = z ? (f32x4){0.f, 0.f, 0.f, 0.f} : r0f[lt];
            rmB[lt] = z ? (f32x4){0.f, 0.f, 0.f, 0.f} : r1f[lt];
        }
        f32x4 eacc[4][2];
#pragma unroll
        for (int lt = 0; lt < 4; lt++)
#pragma unroll
            for (int ch = 0; ch < 2; ch++) eacc[lt][ch] = (f32x4){0.f, 0.f, 0.f, 0.f};

#pragma unroll
        for (int ch = 0; ch < 2; ch++) {
#pragma unroll
            for (int kt = 0; kt < 2; kt++) {
                // reshuffle C-layout r values into B-fragment layout
                float bv[8];
#pragma unroll
                for (int j = 0; j < 8; j++) {
                    int srcLane = ((quad & 1) * 2 + (j >> 2)) * 16 + li;
                    float x0 = ch ? rmB[kt * 2 + 0][j & 3] : rmA[kt * 2 + 0][j & 3];
                    float x1 = ch ? rmB[kt * 2 + 1][j & 3] : rmA[kt * 2 + 1][j & 3];
                    float a = __shfl(x0, srcLane, 64);
                    float bb = __shfl(x1, srcLane, 64);
                    bv[j] = (quad & 2) ? bb : a;
                }
                half8 Bh, Bl;
#pragma unroll
                for (int e = 0; e < 8; e++) {
                    float v = bv[e];
                    float hi = __uint_as_float(__float_as_uint(v) & 0xFFFFE000u);
                    Bh[e] = (_Float16)hi;
                    Bl[e] = (_Float16)(v - hi);
                }
                const _Float16* efb = EF + ((size_t)(layer + 1) * 2 + ch) * 8192
                                      + kt * 2048 + lane * 8;
#pragma unroll
                for (int lt = 0; lt < 4; lt++) {
                    half8 Eh = *(const half8*)(efb + lt * 512);
                    half8 El = *(const half8*)(efb + 4096 + lt * 512);
                    eacc[lt][ch] = __builtin_amdgcn_mfma_f32_16x16x32_f16(Eh, Bh, eacc[lt][ch], 0, 0, 0);
                    eacc[lt][ch] = __builtin_amdgcn_mfma_f32_16x16x32_f16(Eh, Bl, eacc[lt][ch], 0, 0, 0);
                    eacc[lt][ch] = __builtin_amdgcn_mfma_f32_16x16x32_f16(El, Bh, eacc[lt][ch], 0, 0, 0);
                }
            }
        }
        if (cOK) {
            float* sp = stRaw + ((size_t)b * CHK + c) * 128;
#pragma unroll
            for (int ch = 0; ch < 2; ch++)
#pragma unroll
                for (int lt = 0; lt < 4; lt++)
                    *(f32x4*)(sp + ch * 64 + lt * 16 + quad * 4) = eacc[lt][ch];
        }
    }
}

extern "C" void kernel_launch(void* const* d_in, const int* in_sizes, int n_in,
                              void* d_out, int out_size, void* d_ws, size_t ws_size,
                              hipStream_t stream) {
    const float* x         = (const float*)d_in[0];
    const float* W1        = (const float*)d_in[1];
    const float* b1        = (const float*)d_in[2];
    const float* W2        = (const float*)d_in[3];
    const float* b2        = (const float*)d_in[4];
    const float* log_dt    = (const float*)d_in[5];
    const float* log_A_real= (const float*)d_in[6];
    const float* A_imag    = (const float*)d_in[7];
    const float* Cin       = (const float*)d_in[8];
    const float* Dp        = (const float*)d_in[9];
    const float* Wout      = (const float*)d_in[10];
    const float* bout      = (const float*)d_in[11];
    float* out = (float*)d_out;
    float* ws = (float*)d_ws;

    float* U0   = ws + OFF_U0;
    float* U1   = ws + OFF_U1;
    float* S0   = ws + OFF_S0;               // raw states (fp32)
    _Float16* S1 = (_Float16*)(ws + OFF_S1); // w (fp16 hi/lo planes)
    float* lam  = ws + OFF_TAB;
    float* lamT = lam + 512;
    float* Cn   = lamT + 512;
    float* Kt   = Cn + 512;
    float* P    = Kt + 512;
    _Float16* AF = (_Float16*)(P + 32768);
    _Float16* EF = AF + 131072;

    setup_kernel<<<dim3(NL * HH), dim3(64), 0, stream>>>(log_dt, log_A_real, A_imag, Cin,
                                                         lam, lamT, Cn, Kt, P);
    setup2_kernel<<<dim3(NL * HH), dim3(64), 0, stream>>>(Kt, P, AF, EF);
    embed_kernel<<<dim3(BL / 4 / 256), dim3(256), 0, stream>>>(x, W1, b1, U0);
    phaseA_mfma<<<dim3(BB * CPAD / 16), dim3(64), 0, stream>>>(U0, EF, S0);

    float* cur = U0;
    float* nxt = U1;
    for (int i = 0; i < NL; i++) {
        phaseB_kernel<<<dim3(BB), dim3(64), 0, stream>>>(lamT, Cn, S0, S1, i);
        phaseC_mfma<<<dim3(BB * CPAD / 16 / 8), dim3(512), 0, stream>>>(cur, nxt, AF, EF, S1, S0,
                                                                        Dp, Wout, bout, i,
                                                                        W2, b2, out,
                                                                        (i == NL - 1) ? 1 : 0);
        float* tmp = cur; cur = nxt; nxt = tmp;
    }
}